// Round 5
// baseline (217.987 us; speedup 1.0000x reference)
//
#include <hip/hip_runtime.h>
#include <hip/hip_bf16.h>

using floatx4 = __attribute__((ext_vector_type(4))) float;
using int4v   = __attribute__((ext_vector_type(4))) int;
using int8v   = __attribute__((ext_vector_type(8))) int;

#define TEMP_INV 14.285714285714286f  // 1/0.07
#define DD 256    // feature dim; one fp8 row = 256 B
#define BM 128    // cols per ct tile
#define BROWS 64  // rows per gemm block
#define NCT 8     // col tiles/block -> gridDim.x=8 keeps col-group==XCD mapping
#define SC1 127   // e8m0 exponent 127 -> scale 1.0

// ---- kernel 1: L2 normalize -> fp8 e4m3 + exact fp8 diag dot + out zero ----
// 256 thr / 16 rows per block; thread (r = t>>4, s = t&15) owns bytes
// [s*16, s*16+16) of row blockIdx.x*16 + r. Fragment-major p8 destination of
// those 16 bytes is one contiguous 16-B chunk:
//   grp*4096 + (s>>3)*2048 + (s&1)*1024 + ((s>>1)&3)*256 + r*16
// (byte b of row r lands at (b>>7)*2048 + ((b>>4)&1)*1024 + ((b>>5)&3)*256
//  + (r&15)*16 + (b&15) — same formula gemm reads). Within a wave, the 4 r's
// of each s form 4 consecutive 16-B chunks -> 16 x 64-B coalesced segments.
__global__ __launch_bounds__(256) void nrm_kernel(
    const float* __restrict__ anchor, const float* __restrict__ positive,
    unsigned char* __restrict__ a8, unsigned char* __restrict__ p8,
    float* __restrict__ diag, float* __restrict__ out) {
  if (blockIdx.x == 0 && threadIdx.x == 0) out[0] = 0.f;  // stream-order visible
  const int t = threadIdx.x;
  const int s = t & 15;               // 16-float segment within the row
  const int r = t >> 4;               // row within the 16-row group
  const int row = blockIdx.x * 16 + r;
  const float4* av = (const float4*)(anchor   + (size_t)row * DD + s * 16);
  const float4* pv = (const float4*)(positive + (size_t)row * DD + s * 16);
  float4 va[4], vp[4];
  float sa = 0.f, sp = 0.f;
#pragma unroll
  for (int k = 0; k < 4; ++k) {
    va[k] = av[k]; vp[k] = pv[k];
    sa += va[k].x * va[k].x + va[k].y * va[k].y + va[k].z * va[k].z + va[k].w * va[k].w;
    sp += vp[k].x * vp[k].x + vp[k].y * vp[k].y + vp[k].z * vp[k].z + vp[k].w * vp[k].w;
  }
  // reduce over the 16 threads of this row (lanes (r&3)*16 + s, s=0..15)
#pragma unroll
  for (int m = 1; m < 16; m <<= 1) {
    sa += __shfl_xor(sa, m, 16);
    sp += __shfl_xor(sp, m, 16);
  }
  const float ka = 1.0f / fmaxf(sqrtf(sa), 1e-12f);
  const float kp = 1.0f / fmaxf(sqrtf(sp), 1e-12f);
  int pa[4], pq[4];
#pragma unroll
  for (int k = 0; k < 4; ++k) {
    int x = __builtin_amdgcn_cvt_pk_fp8_f32(va[k].x * ka, va[k].y * ka, 0, false);
    pa[k] = __builtin_amdgcn_cvt_pk_fp8_f32(va[k].z * ka, va[k].w * ka, x, true);
    int y = __builtin_amdgcn_cvt_pk_fp8_f32(vp[k].x * kp, vp[k].y * kp, 0, false);
    pq[k] = __builtin_amdgcn_cvt_pk_fp8_f32(vp[k].z * kp, vp[k].w * kp, y, true);
  }
  // a8 row-major, 16 B/thread, coalesced
  *(int4v*)(a8 + (size_t)row * DD + s * 16) = (int4v){pa[0], pa[1], pa[2], pa[3]};
  // p8 fragment-major, 16 B/thread, 64-B-coalesced across lanes
  {
    const unsigned int off = (unsigned)blockIdx.x * 4096 + ((s >> 3) << 11)
                           + ((s & 1) << 10) + (((s >> 1) & 3) << 8) + (r << 4);
    *(int4v*)(p8 + off) = (int4v){pq[0], pq[1], pq[2], pq[3]};
  }
  // exact quantized dot partial over this thread's 16 elements
  float d = 0.f;
#pragma unroll
  for (int k = 0; k < 4; ++k) {
    d += __builtin_amdgcn_cvt_f32_fp8(pa[k], 0) * __builtin_amdgcn_cvt_f32_fp8(pq[k], 0)
       + __builtin_amdgcn_cvt_f32_fp8(pa[k], 1) * __builtin_amdgcn_cvt_f32_fp8(pq[k], 1)
       + __builtin_amdgcn_cvt_f32_fp8(pa[k], 2) * __builtin_amdgcn_cvt_f32_fp8(pq[k], 2)
       + __builtin_amdgcn_cvt_f32_fp8(pa[k], 3) * __builtin_amdgcn_cvt_f32_fp8(pq[k], 3);
  }
#pragma unroll
  for (int m = 1; m < 16; m <<= 1) d += __shfl_xor(d, m, 16);
  if (s == 0) diag[row] = d;
}

// A fragment straight from global (row-major, per-lane gather, once/kernel).
__device__ __forceinline__ int8v fragG(const unsigned char* g) {
  const int4v lo = *(const int4v*)(g);
  const int4v hi = *(const int4v*)(g + 16);
  return __builtin_shufflevector(lo, hi, 0, 1, 2, 3, 4, 5, 6, 7);
}

__device__ __forceinline__ floatx4 mfma_sc(int8v a, int8v b, floatx4 c) {
  return __builtin_amdgcn_mfma_scale_f32_16x16x128_f8f6f4(a, b, c, 0, 0, 0,
                                                          SC1, 0, SC1);
}

// ------ kernel 2: grid (8,128) x 512 thr -> 1024 blocks = 4/CU = 32 waves/CU.
// R4's barrier-free direct-VMEM structure kept verbatim; the one change is
// OCCUPANCY: all pipes were <35% with the structure-invariant 46 µs at the
// grid-capped 16 waves/CU -> latency-bound; 8 waves/SIMD doubles the hiding.
// gridDim.x=8 preserves wgid%8 = col-group == XCD (R0-vs-R3: worth ~20 µs).
// __launch_bounds__(512,8): VGPR<=64 so the RF admits 8 waves/SIMD.
__global__ __launch_bounds__(512, 8) void gemm_stats(
    const unsigned char* __restrict__ a8, const unsigned char* __restrict__ p8,
    float* __restrict__ rsum, float* __restrict__ rmax, int Btot) {
  __shared__ float red_sum[4][BROWS];
  __shared__ float red_max[4][BROWS];

  const int t = threadIdx.x;
  const int wave = t >> 6, lane = t & 63;
  const int wm = wave & 1, wn = wave >> 1;      // 2 row-groups x 4 col-groups
  const int quad = lane >> 4, l16 = lane & 15;
  const int row0    = blockIdx.y * BROWS;
  const int colbase = blockIdx.x * (NCT * BM);
  const bool hasdiag = ((int)(blockIdx.y >> 4) == (int)blockIdx.x);

  // ---- A fragments: 16 VGPRs, ct-invariant ----
  // rows row0 + wm*32 + mi*16 + l16, K bytes [ks*128 + quad*32, +32)
  int8v a_frag[2][2];
  {
    const unsigned char* ab =
        a8 + (size_t)(row0 + wm * 32 + l16) * DD + quad * 32;
#pragma unroll
    for (int mi = 0; mi < 2; ++mi)
#pragma unroll
      for (int ks = 0; ks < 2; ++ks)
        a_frag[mi][ks] = fragG(ab + mi * 16 * DD + ks * 128);
  }

  float se_run[2][4], mx_run[2][4];
#pragma unroll
  for (int a = 0; a < 2; ++a)
#pragma unroll
    for (int b = 0; b < 4; ++b) { se_run[a][b] = 0.f; mx_run[a][b] = -INFINITY; }

  for (int ct = 0; ct < NCT; ++ct) {
    const int col0 = colbase + ct * BM;
    // fragment-major base for this wave's 32 B-rows (16-aligned X -> X*256)
    const unsigned char* bb = p8 + (size_t)(col0 + wn * 32) * DD + lane * 16;

    floatx4 acc[2][2];
#pragma unroll
    for (int a = 0; a < 2; ++a)
#pragma unroll
      for (int b = 0; b < 2; ++b) acc[a][b] = (floatx4){0.f, 0.f, 0.f, 0.f};

#pragma unroll
    for (int ks = 0; ks < 2; ++ks) {
#pragma unroll
      for (int ni = 0; ni < 2; ++ni) {
        const unsigned char* c = bb + ni * 4096 + ks * 2048;
        const int4v lo = *(const int4v*)(c);          // contiguous 1 KB/wave
        const int4v hi = *(const int4v*)(c + 1024);   // contiguous 1 KB/wave
        const int8v bf = __builtin_shufflevector(lo, hi, 0, 1, 2, 3, 4, 5, 6, 7);
        acc[0][ni] = mfma_sc(a_frag[0][ks], bf, acc[0][ni]);
        acc[1][ni] = mfma_sc(a_frag[1][ks], bf, acc[1][ni]);
      }
    }

    // ---- fused stats epilogue (C/D: col=lane&15, row=quad*4+reg) ----
    if (!hasdiag) {
#pragma unroll
      for (int mi = 0; mi < 2; ++mi)
#pragma unroll
        for (int reg = 0; reg < 4; ++reg)
#pragma unroll
          for (int ni = 0; ni < 2; ++ni) {
            const float s = acc[mi][ni][reg];
            se_run[mi][reg] += __expf(s * TEMP_INV);
            mx_run[mi][reg] = fmaxf(mx_run[mi][reg], s);
          }
    } else {
#pragma unroll
      for (int mi = 0; mi < 2; ++mi)
#pragma unroll
        for (int reg = 0; reg < 4; ++reg) {
          const int i = row0 + wm * 32 + mi * 16 + quad * 4 + reg;
#pragma unroll
          for (int ni = 0; ni < 2; ++ni) {
            const float s = acc[mi][ni][reg];
            const int j = col0 + wn * 32 + ni * 16 + l16;
            se_run[mi][reg] += __expf(s * TEMP_INV);
            mx_run[mi][reg] = fmaxf(mx_run[mi][reg], (i == j) ? -INFINITY : s);
          }
        }
    }
  }

  // 16-lane cross reduction, then cross-wave combine via 2 KB LDS
#pragma unroll
  for (int mi = 0; mi < 2; ++mi) {
#pragma unroll
    for (int reg = 0; reg < 4; ++reg) {
      float se = se_run[mi][reg], mx = mx_run[mi][reg];
#pragma unroll
      for (int m = 1; m < 16; m <<= 1) {
        se += __shfl_xor(se, m, 64);
        mx = fmaxf(mx, __shfl_xor(mx, m, 64));
      }
      if (l16 == 0) {
        const int rb = wm * 32 + mi * 16 + quad * 4 + reg;
        red_sum[wn][rb] = se;
        red_max[wn][rb] = mx;
      }
    }
  }
  __syncthreads();
  if (t < BROWS) {
    rsum[(size_t)blockIdx.x * Btot + row0 + t] =
        (red_sum[0][t] + red_sum[1][t]) + (red_sum[2][t] + red_sum[3][t]);
    rmax[(size_t)blockIdx.x * Btot + row0 + t] =
        fmaxf(fmaxf(red_max[0][t], red_max[1][t]),
              fmaxf(red_max[2][t], red_max[3][t]));
  }
}

// ---- kernel 3: per-row loss from partials, block-reduce, atomic mean ----
__global__ __launch_bounds__(256) void row_loss_kernel(
    const float* __restrict__ rsum, const float* __restrict__ rmax,
    const float* __restrict__ diag, float* __restrict__ out, int Btot, int NG) {
  const int i = blockIdx.x * 256 + threadIdx.x;
  float s = 0.f, m = -INFINITY;
  for (int c = 0; c < NG; ++c) {
    s += rsum[(size_t)c * Btot + i];
    m = fmaxf(m, rmax[(size_t)c * Btot + i]);
  }
  float rl = __logf(s + __expf(m * TEMP_INV)) - diag[i] * TEMP_INV;
#pragma unroll
  for (int mm = 32; mm >= 1; mm >>= 1) rl += __shfl_xor(rl, mm, 64);
  __shared__ float red[4];
  if ((threadIdx.x & 63) == 0) red[threadIdx.x >> 6] = rl;
  __syncthreads();
  if (threadIdx.x == 0)
    atomicAdd(out, (red[0] + red[1] + red[2] + red[3]) / (float)Btot);
}

extern "C" void kernel_launch(void* const* d_in, const int* in_sizes, int n_in,
                              void* d_out, int out_size, void* d_ws, size_t ws_size,
                              hipStream_t stream) {
  const float* anchor   = (const float*)d_in[0];
  const float* positive = (const float*)d_in[1];
  const int B  = in_sizes[0] / DD;     // 8192
  const int NG = B / (BM * NCT);       // 8 column groups
  const size_t BD = (size_t)B * DD;

  // ws: a8(2MB) | p8(2MB, fragment-major) | rsum(NG*B) | rmax(NG*B) | diag(B)
  unsigned char* a8 = (unsigned char*)d_ws;
  unsigned char* p8 = a8 + BD;
  float* rsum  = (float*)(p8 + BD);
  float* rmax  = rsum + (size_t)NG * B;
  float* diag  = rmax + (size_t)NG * B;

  nrm_kernel<<<B / 16, 256, 0, stream>>>(anchor, positive, a8, p8, diag,
                                         (float*)d_out);
  dim3 g2(NG, B / BROWS);
  gemm_stats<<<g2, 512, 0, stream>>>(a8, p8, rsum, rmax, B);
  row_loss_kernel<<<B / 256, 256, 0, stream>>>(rsum, rmax, diag, (float*)d_out, B, NG);
}

// Round 6
// 190.342 us; speedup vs baseline: 1.1452x; 1.1452x over previous
//
#include <hip/hip_runtime.h>
#include <hip/hip_bf16.h>

using floatx4 = __attribute__((ext_vector_type(4))) float;
using int4v   = __attribute__((ext_vector_type(4))) int;
using int8v   = __attribute__((ext_vector_type(8))) int;

#define TEMP_INV 14.285714285714286f  // 1/0.07
#define DD 256    // feature dim; one fp8 row = 256 B
#define BM 128    // cols per ct tile
#define BROWS 64  // rows per gemm block
#define NCT 8     // col tiles/block -> gridDim.x=8 keeps col-group==XCD mapping
#define SC1 127   // e8m0 exponent 127 -> scale 1.0

// ---- kernel 1: L2 normalize -> fp8 e4m3 + exact fp8 diag dot + out zero ----
// 256 thr / 16 rows per block; thread (r = t>>4, s = t&15) owns bytes
// [s*16, s*16+16) of row blockIdx.x*16 + r. Fragment-major p8 destination of
// those 16 bytes is one contiguous 16-B chunk (64-B coalesced across lanes).
__global__ __launch_bounds__(256) void nrm_kernel(
    const float* __restrict__ anchor, const float* __restrict__ positive,
    unsigned char* __restrict__ a8, unsigned char* __restrict__ p8,
    float* __restrict__ diag, float* __restrict__ out) {
  if (blockIdx.x == 0 && threadIdx.x == 0) out[0] = 0.f;  // stream-order visible
  const int t = threadIdx.x;
  const int s = t & 15;               // 16-float segment within the row
  const int r = t >> 4;               // row within the 16-row group
  const int row = blockIdx.x * 16 + r;
  const float4* av = (const float4*)(anchor   + (size_t)row * DD + s * 16);
  const float4* pv = (const float4*)(positive + (size_t)row * DD + s * 16);
  float4 va[4], vp[4];
  float sa = 0.f, sp = 0.f;
#pragma unroll
  for (int k = 0; k < 4; ++k) {
    va[k] = av[k]; vp[k] = pv[k];
    sa += va[k].x * va[k].x + va[k].y * va[k].y + va[k].z * va[k].z + va[k].w * va[k].w;
    sp += vp[k].x * vp[k].x + vp[k].y * vp[k].y + vp[k].z * vp[k].z + vp[k].w * vp[k].w;
  }
  // reduce over the 16 threads of this row (lanes (r&3)*16 + s, s=0..15)
#pragma unroll
  for (int m = 1; m < 16; m <<= 1) {
    sa += __shfl_xor(sa, m, 16);
    sp += __shfl_xor(sp, m, 16);
  }
  const float ka = 1.0f / fmaxf(sqrtf(sa), 1e-12f);
  const float kp = 1.0f / fmaxf(sqrtf(sp), 1e-12f);
  int pa[4], pq[4];
#pragma unroll
  for (int k = 0; k < 4; ++k) {
    int x = __builtin_amdgcn_cvt_pk_fp8_f32(va[k].x * ka, va[k].y * ka, 0, false);
    pa[k] = __builtin_amdgcn_cvt_pk_fp8_f32(va[k].z * ka, va[k].w * ka, x, true);
    int y = __builtin_amdgcn_cvt_pk_fp8_f32(vp[k].x * kp, vp[k].y * kp, 0, false);
    pq[k] = __builtin_amdgcn_cvt_pk_fp8_f32(vp[k].z * kp, vp[k].w * kp, y, true);
  }
  // a8 row-major, 16 B/thread, coalesced
  *(int4v*)(a8 + (size_t)row * DD + s * 16) = (int4v){pa[0], pa[1], pa[2], pa[3]};
  // p8 fragment-major, 16 B/thread, 64-B-coalesced across lanes
  {
    const unsigned int off = (unsigned)blockIdx.x * 4096 + ((s >> 3) << 11)
                           + ((s & 1) << 10) + (((s >> 1) & 3) << 8) + (r << 4);
    *(int4v*)(p8 + off) = (int4v){pq[0], pq[1], pq[2], pq[3]};
  }
  // exact quantized dot partial over this thread's 16 elements
  float d = 0.f;
#pragma unroll
  for (int k = 0; k < 4; ++k) {
    d += __builtin_amdgcn_cvt_f32_fp8(pa[k], 0) * __builtin_amdgcn_cvt_f32_fp8(pq[k], 0)
       + __builtin_amdgcn_cvt_f32_fp8(pa[k], 1) * __builtin_amdgcn_cvt_f32_fp8(pq[k], 1)
       + __builtin_amdgcn_cvt_f32_fp8(pa[k], 2) * __builtin_amdgcn_cvt_f32_fp8(pq[k], 2)
       + __builtin_amdgcn_cvt_f32_fp8(pa[k], 3) * __builtin_amdgcn_cvt_f32_fp8(pq[k], 3);
  }
#pragma unroll
  for (int m = 1; m < 16; m <<= 1) d += __shfl_xor(d, m, 16);
  if (s == 0) diag[row] = d;
}

// A fragment straight from global (row-major, per-lane gather, once/kernel).
__device__ __forceinline__ int8v fragG(const unsigned char* g) {
  const int4v lo = *(const int4v*)(g);
  const int4v hi = *(const int4v*)(g + 16);
  return __builtin_shufflevector(lo, hi, 0, 1, 2, 3, 4, 5, 6, 7);
}

__device__ __forceinline__ floatx4 mfma_sc(int8v a, int8v b, floatx4 c) {
  return __builtin_amdgcn_mfma_scale_f32_16x16x128_f8f6f4(a, b, c, 0, 0, 0,
                                                          SC1, 0, SC1);
}

// ------ kernel 2: grid (8,128) x 512 thr. Clean occupancy A/B vs R4/R5: ------
// R5's (512,8) forced VGPR=32 -> ~200 MB scratch spill (WRITE 19->220 MB),
// which buried the occupancy gain (Occ did rise 32->72%). (512,6) gives the
// compiler ~80-84 VGPRs (working set ~70 -> NO spill) and 6 waves/SIMD =
// 24 waves/CU, 1.5x R4's grid-capped 16. Everything else identical to R4:
// barrier-free main loop, fragment-major B (contiguous 1 KB wave loads),
// A fragments ct-invariant in registers, gridDim.x=8 = col-group = XCD.
__global__ __launch_bounds__(512, 6) void gemm_stats(
    const unsigned char* __restrict__ a8, const unsigned char* __restrict__ p8,
    float* __restrict__ rsum, float* __restrict__ rmax, int Btot) {
  __shared__ float red_sum[4][BROWS];
  __shared__ float red_max[4][BROWS];

  const int t = threadIdx.x;
  const int wave = t >> 6, lane = t & 63;
  const int wm = wave & 1, wn = wave >> 1;      // 2 row-groups x 4 col-groups
  const int quad = lane >> 4, l16 = lane & 15;
  const int row0    = blockIdx.y * BROWS;
  const int colbase = blockIdx.x * (NCT * BM);
  const bool hasdiag = ((int)(blockIdx.y >> 4) == (int)blockIdx.x);

  // ---- A fragments: 16 VGPRs, ct-invariant ----
  // rows row0 + wm*32 + mi*16 + l16, K bytes [ks*128 + quad*32, +32)
  int8v a_frag[2][2];
  {
    const unsigned char* ab =
        a8 + (size_t)(row0 + wm * 32 + l16) * DD + quad * 32;
#pragma unroll
    for (int mi = 0; mi < 2; ++mi)
#pragma unroll
      for (int ks = 0; ks < 2; ++ks)
        a_frag[mi][ks] = fragG(ab + mi * 16 * DD + ks * 128);
  }

  float se_run[2][4], mx_run[2][4];
#pragma unroll
  for (int a = 0; a < 2; ++a)
#pragma unroll
    for (int b = 0; b < 4; ++b) { se_run[a][b] = 0.f; mx_run[a][b] = -INFINITY; }

  for (int ct = 0; ct < NCT; ++ct) {
    const int col0 = colbase + ct * BM;
    // fragment-major base for this wave's 32 B-rows (16-aligned X -> X*256)
    const unsigned char* bb = p8 + (size_t)(col0 + wn * 32) * DD + lane * 16;

    floatx4 acc[2][2];
#pragma unroll
    for (int a = 0; a < 2; ++a)
#pragma unroll
      for (int b = 0; b < 2; ++b) acc[a][b] = (floatx4){0.f, 0.f, 0.f, 0.f};

#pragma unroll
    for (int ks = 0; ks < 2; ++ks) {
#pragma unroll
      for (int ni = 0; ni < 2; ++ni) {
        const unsigned char* c = bb + ni * 4096 + ks * 2048;
        const int4v lo = *(const int4v*)(c);          // contiguous 1 KB/wave
        const int4v hi = *(const int4v*)(c + 1024);   // contiguous 1 KB/wave
        const int8v bf = __builtin_shufflevector(lo, hi, 0, 1, 2, 3, 4, 5, 6, 7);
        acc[0][ni] = mfma_sc(a_frag[0][ks], bf, acc[0][ni]);
        acc[1][ni] = mfma_sc(a_frag[1][ks], bf, acc[1][ni]);
      }
    }

    // ---- fused stats epilogue (C/D: col=lane&15, row=quad*4+reg) ----
    if (!hasdiag) {
#pragma unroll
      for (int mi = 0; mi < 2; ++mi)
#pragma unroll
        for (int reg = 0; reg < 4; ++reg)
#pragma unroll
          for (int ni = 0; ni < 2; ++ni) {
            const float s = acc[mi][ni][reg];
            se_run[mi][reg] += __expf(s * TEMP_INV);
            mx_run[mi][reg] = fmaxf(mx_run[mi][reg], s);
          }
    } else {
#pragma unroll
      for (int mi = 0; mi < 2; ++mi)
#pragma unroll
        for (int reg = 0; reg < 4; ++reg) {
          const int i = row0 + wm * 32 + mi * 16 + quad * 4 + reg;
#pragma unroll
          for (int ni = 0; ni < 2; ++ni) {
            const float s = acc[mi][ni][reg];
            const int j = col0 + wn * 32 + ni * 16 + l16;
            se_run[mi][reg] += __expf(s * TEMP_INV);
            mx_run[mi][reg] = fmaxf(mx_run[mi][reg], (i == j) ? -INFINITY : s);
          }
        }
    }
  }

  // 16-lane cross reduction, then cross-wave combine via 2 KB LDS
#pragma unroll
  for (int mi = 0; mi < 2; ++mi) {
#pragma unroll
    for (int reg = 0; reg < 4; ++reg) {
      float se = se_run[mi][reg], mx = mx_run[mi][reg];
#pragma unroll
      for (int m = 1; m < 16; m <<= 1) {
        se += __shfl_xor(se, m, 64);
        mx = fmaxf(mx, __shfl_xor(mx, m, 64));
      }
      if (l16 == 0) {
        const int rb = wm * 32 + mi * 16 + quad * 4 + reg;
        red_sum[wn][rb] = se;
        red_max[wn][rb] = mx;
      }
    }
  }
  __syncthreads();
  if (t < BROWS) {
    rsum[(size_t)blockIdx.x * Btot + row0 + t] =
        (red_sum[0][t] + red_sum[1][t]) + (red_sum[2][t] + red_sum[3][t]);
    rmax[(size_t)blockIdx.x * Btot + row0 + t] =
        fmaxf(fmaxf(red_max[0][t], red_max[1][t]),
              fmaxf(red_max[2][t], red_max[3][t]));
  }
}

// ---- kernel 3: per-row loss from partials, block-reduce, atomic mean ----
__global__ __launch_bounds__(256) void row_loss_kernel(
    const float* __restrict__ rsum, const float* __restrict__ rmax,
    const float* __restrict__ diag, float* __restrict__ out, int Btot, int NG) {
  const int i = blockIdx.x * 256 + threadIdx.x;
  float s = 0.f, m = -INFINITY;
  for (int c = 0; c < NG; ++c) {
    s += rsum[(size_t)c * Btot + i];
    m = fmaxf(m, rmax[(size_t)c * Btot + i]);
  }
  float rl = __logf(s + __expf(m * TEMP_INV)) - diag[i] * TEMP_INV;
#pragma unroll
  for (int mm = 32; mm >= 1; mm >>= 1) rl += __shfl_xor(rl, mm, 64);
  __shared__ float red[4];
  if ((threadIdx.x & 63) == 0) red[threadIdx.x >> 6] = rl;
  __syncthreads();
  if (threadIdx.x == 0)
    atomicAdd(out, (red[0] + red[1] + red[2] + red[3]) / (float)Btot);
}

extern "C" void kernel_launch(void* const* d_in, const int* in_sizes, int n_in,
                              void* d_out, int out_size, void* d_ws, size_t ws_size,
                              hipStream_t stream) {
  const float* anchor   = (const float*)d_in[0];
  const float* positive = (const float*)d_in[1];
  const int B  = in_sizes[0] / DD;     // 8192
  const int NG = B / (BM * NCT);       // 8 column groups
  const size_t BD = (size_t)B * DD;

  // ws: a8(2MB) | p8(2MB, fragment-major) | rsum(NG*B) | rmax(NG*B) | diag(B)
  unsigned char* a8 = (unsigned char*)d_ws;
  unsigned char* p8 = a8 + BD;
  float* rsum  = (float*)(p8 + BD);
  float* rmax  = rsum + (size_t)NG * B;
  float* diag  = rmax + (size_t)NG * B;

  nrm_kernel<<<B / 16, 256, 0, stream>>>(anchor, positive, a8, p8, diag,
                                         (float*)d_out);
  dim3 g2(NG, B / BROWS);
  gemm_stats<<<g2, 512, 0, stream>>>(a8, p8, rsum, rmax, B);
  row_loss_kernel<<<B / 256, 256, 0, stream>>>(rsum, rmax, diag, (float*)d_out, B, NG);
}

// Round 7
// 102.693 us; speedup vs baseline: 2.1227x; 1.8535x over previous
//
#include <hip/hip_runtime.h>
#include <hip/hip_bf16.h>

using floatx4 = __attribute__((ext_vector_type(4))) float;
using int4v   = __attribute__((ext_vector_type(4))) int;
using int8v   = __attribute__((ext_vector_type(8))) int;

#define TEMP_INV 14.285714285714286f  // 1/0.07
#define DD 256    // feature dim; one fp8 row = 256 B
#define BM 128    // cols per ct tile
#define BROWS 64  // rows per gemm block
#define NCT 8     // col tiles/block -> gridDim.x=8 keeps col-group==XCD mapping
#define SC1 127   // e8m0 exponent 127 -> scale 1.0

// ---- kernel 1: L2 normalize -> fp8 e4m3 + exact fp8 diag dot + out zero ----
// 256 thr / 16 rows per block; thread (r = t>>4, s = t&15) owns bytes
// [s*16, s*16+16) of row blockIdx.x*16 + r. Fragment-major p8 destination of
// those 16 bytes is one contiguous 16-B chunk (64-B coalesced across lanes).
__global__ __launch_bounds__(256) void nrm_kernel(
    const float* __restrict__ anchor, const float* __restrict__ positive,
    unsigned char* __restrict__ a8, unsigned char* __restrict__ p8,
    float* __restrict__ diag, float* __restrict__ out) {
  if (blockIdx.x == 0 && threadIdx.x == 0) out[0] = 0.f;  // stream-order visible
  const int t = threadIdx.x;
  const int s = t & 15;               // 16-float segment within the row
  const int r = t >> 4;               // row within the 16-row group
  const int row = blockIdx.x * 16 + r;
  const float4* av = (const float4*)(anchor   + (size_t)row * DD + s * 16);
  const float4* pv = (const float4*)(positive + (size_t)row * DD + s * 16);
  float4 va[4], vp[4];
  float sa = 0.f, sp = 0.f;
#pragma unroll
  for (int k = 0; k < 4; ++k) {
    va[k] = av[k]; vp[k] = pv[k];
    sa += va[k].x * va[k].x + va[k].y * va[k].y + va[k].z * va[k].z + va[k].w * va[k].w;
    sp += vp[k].x * vp[k].x + vp[k].y * vp[k].y + vp[k].z * vp[k].z + vp[k].w * vp[k].w;
  }
  // reduce over the 16 threads of this row (lanes (r&3)*16 + s, s=0..15)
#pragma unroll
  for (int m = 1; m < 16; m <<= 1) {
    sa += __shfl_xor(sa, m, 16);
    sp += __shfl_xor(sp, m, 16);
  }
  const float ka = 1.0f / fmaxf(sqrtf(sa), 1e-12f);
  const float kp = 1.0f / fmaxf(sqrtf(sp), 1e-12f);
  int pa[4], pq[4];
#pragma unroll
  for (int k = 0; k < 4; ++k) {
    int x = __builtin_amdgcn_cvt_pk_fp8_f32(va[k].x * ka, va[k].y * ka, 0, false);
    pa[k] = __builtin_amdgcn_cvt_pk_fp8_f32(va[k].z * ka, va[k].w * ka, x, true);
    int y = __builtin_amdgcn_cvt_pk_fp8_f32(vp[k].x * kp, vp[k].y * kp, 0, false);
    pq[k] = __builtin_amdgcn_cvt_pk_fp8_f32(vp[k].z * kp, vp[k].w * kp, y, true);
  }
  // a8 row-major, 16 B/thread, coalesced
  *(int4v*)(a8 + (size_t)row * DD + s * 16) = (int4v){pa[0], pa[1], pa[2], pa[3]};
  // p8 fragment-major, 16 B/thread, 64-B-coalesced across lanes
  {
    const unsigned int off = (unsigned)blockIdx.x * 4096 + ((s >> 3) << 11)
                           + ((s & 1) << 10) + (((s >> 1) & 3) << 8) + (r << 4);
    *(int4v*)(p8 + off) = (int4v){pq[0], pq[1], pq[2], pq[3]};
  }
  // exact quantized dot partial over this thread's 16 elements
  float d = 0.f;
#pragma unroll
  for (int k = 0; k < 4; ++k) {
    d += __builtin_amdgcn_cvt_f32_fp8(pa[k], 0) * __builtin_amdgcn_cvt_f32_fp8(pq[k], 0)
       + __builtin_amdgcn_cvt_f32_fp8(pa[k], 1) * __builtin_amdgcn_cvt_f32_fp8(pq[k], 1)
       + __builtin_amdgcn_cvt_f32_fp8(pa[k], 2) * __builtin_amdgcn_cvt_f32_fp8(pq[k], 2)
       + __builtin_amdgcn_cvt_f32_fp8(pa[k], 3) * __builtin_amdgcn_cvt_f32_fp8(pq[k], 3);
  }
#pragma unroll
  for (int m = 1; m < 16; m <<= 1) d += __shfl_xor(d, m, 16);
  if (s == 0) diag[row] = d;
}

// A fragment straight from global (row-major, per-lane gather, once/kernel).
__device__ __forceinline__ int8v fragG(const unsigned char* g) {
  const int4v lo = *(const int4v*)(g);
  const int4v hi = *(const int4v*)(g + 16);
  return __builtin_shufflevector(lo, hi, 0, 1, 2, 3, 4, 5, 6, 7);
}

__device__ __forceinline__ floatx4 mfma_sc(int8v a, int8v b, floatx4 c) {
  return __builtin_amdgcn_mfma_scale_f32_16x16x128_f8f6f4(a, b, c, 0, 0, 0,
                                                          SC1, 0, SC1);
}

// ------ kernel 2: grid (8,128) x 512 thr; the CLEAN occupancy experiment ------
// Register-cap ladder: (512,4)->64 VGPR no spill (R4); (512,6)->40+40 split,
// spill, +230 MB scratch (R6); (512,8)->32+32, worse (R5). So: keep the
// 4-blocks/CU grid AND the no-spill cap. With VGPR<=64 the RF itself admits
// 8 waves/SIMD -> the 4 resident blocks give 32 waves/CU with no forced
// allocation; at ~72 we'd get 3 blocks = 24 waves/CU, still no spill.
// Everything else identical to R4/R6: barrier-free main loop, fragment-major
// B (contiguous 1 KB wave loads), A fragments ct-invariant in registers,
// gridDim.x=8 = col-group = XCD (worth ~20 us, R0-vs-R3).
__global__ __launch_bounds__(512, 4) void gemm_stats(
    const unsigned char* __restrict__ a8, const unsigned char* __restrict__ p8,
    float* __restrict__ rsum, float* __restrict__ rmax, int Btot) {
  __shared__ float red_sum[4][BROWS];
  __shared__ float red_max[4][BROWS];

  const int t = threadIdx.x;
  const int wave = t >> 6, lane = t & 63;
  const int wm = wave & 1, wn = wave >> 1;      // 2 row-groups x 4 col-groups
  const int quad = lane >> 4, l16 = lane & 15;
  const int row0    = blockIdx.y * BROWS;
  const int colbase = blockIdx.x * (NCT * BM);
  const bool hasdiag = ((int)(blockIdx.y >> 4) == (int)blockIdx.x);

  // ---- A fragments: 16 VGPRs, ct-invariant ----
  // rows row0 + wm*32 + mi*16 + l16, K bytes [ks*128 + quad*32, +32)
  int8v a_frag[2][2];
  {
    const unsigned char* ab =
        a8 + (size_t)(row0 + wm * 32 + l16) * DD + quad * 32;
#pragma unroll
    for (int mi = 0; mi < 2; ++mi)
#pragma unroll
      for (int ks = 0; ks < 2; ++ks)
        a_frag[mi][ks] = fragG(ab + mi * 16 * DD + ks * 128);
  }

  float se_run[2][4], mx_run[2][4];
#pragma unroll
  for (int a = 0; a < 2; ++a)
#pragma unroll
    for (int b = 0; b < 4; ++b) { se_run[a][b] = 0.f; mx_run[a][b] = -INFINITY; }

  for (int ct = 0; ct < NCT; ++ct) {
    const int col0 = colbase + ct * BM;
    // fragment-major base for this wave's 32 B-rows (16-aligned X -> X*256)
    const unsigned char* bb = p8 + (size_t)(col0 + wn * 32) * DD + lane * 16;

    floatx4 acc[2][2];
#pragma unroll
    for (int a = 0; a < 2; ++a)
#pragma unroll
      for (int b = 0; b < 2; ++b) acc[a][b] = (floatx4){0.f, 0.f, 0.f, 0.f};

#pragma unroll
    for (int ks = 0; ks < 2; ++ks) {
#pragma unroll
      for (int ni = 0; ni < 2; ++ni) {
        const unsigned char* c = bb + ni * 4096 + ks * 2048;
        const int4v lo = *(const int4v*)(c);          // contiguous 1 KB/wave
        const int4v hi = *(const int4v*)(c + 1024);   // contiguous 1 KB/wave
        const int8v bf = __builtin_shufflevector(lo, hi, 0, 1, 2, 3, 4, 5, 6, 7);
        acc[0][ni] = mfma_sc(a_frag[0][ks], bf, acc[0][ni]);
        acc[1][ni] = mfma_sc(a_frag[1][ks], bf, acc[1][ni]);
      }
    }

    // ---- fused stats epilogue (C/D: col=lane&15, row=quad*4+reg) ----
    if (!hasdiag) {
#pragma unroll
      for (int mi = 0; mi < 2; ++mi)
#pragma unroll
        for (int reg = 0; reg < 4; ++reg)
#pragma unroll
          for (int ni = 0; ni < 2; ++ni) {
            const float s = acc[mi][ni][reg];
            se_run[mi][reg] += __expf(s * TEMP_INV);
            mx_run[mi][reg] = fmaxf(mx_run[mi][reg], s);
          }
    } else {
#pragma unroll
      for (int mi = 0; mi < 2; ++mi)
#pragma unroll
        for (int reg = 0; reg < 4; ++reg) {
          const int i = row0 + wm * 32 + mi * 16 + quad * 4 + reg;
#pragma unroll
          for (int ni = 0; ni < 2; ++ni) {
            const float s = acc[mi][ni][reg];
            const int j = col0 + wn * 32 + ni * 16 + l16;
            se_run[mi][reg] += __expf(s * TEMP_INV);
            mx_run[mi][reg] = fmaxf(mx_run[mi][reg], (i == j) ? -INFINITY : s);
          }
        }
    }
  }

  // 16-lane cross reduction, then cross-wave combine via 2 KB LDS
#pragma unroll
  for (int mi = 0; mi < 2; ++mi) {
#pragma unroll
    for (int reg = 0; reg < 4; ++reg) {
      float se = se_run[mi][reg], mx = mx_run[mi][reg];
#pragma unroll
      for (int m = 1; m < 16; m <<= 1) {
        se += __shfl_xor(se, m, 64);
        mx = fmaxf(mx, __shfl_xor(mx, m, 64));
      }
      if (l16 == 0) {
        const int rb = wm * 32 + mi * 16 + quad * 4 + reg;
        red_sum[wn][rb] = se;
        red_max[wn][rb] = mx;
      }
    }
  }
  __syncthreads();
  if (t < BROWS) {
    rsum[(size_t)blockIdx.x * Btot + row0 + t] =
        (red_sum[0][t] + red_sum[1][t]) + (red_sum[2][t] + red_sum[3][t]);
    rmax[(size_t)blockIdx.x * Btot + row0 + t] =
        fmaxf(fmaxf(red_max[0][t], red_max[1][t]),
              fmaxf(red_max[2][t], red_max[3][t]));
  }
}

// ---- kernel 3: per-row loss from partials, block-reduce, atomic mean ----
__global__ __launch_bounds__(256) void row_loss_kernel(
    const float* __restrict__ rsum, const float* __restrict__ rmax,
    const float* __restrict__ diag, float* __restrict__ out, int Btot, int NG) {
  const int i = blockIdx.x * 256 + threadIdx.x;
  float s = 0.f, m = -INFINITY;
  for (int c = 0; c < NG; ++c) {
    s += rsum[(size_t)c * Btot + i];
    m = fmaxf(m, rmax[(size_t)c * Btot + i]);
  }
  float rl = __logf(s + __expf(m * TEMP_INV)) - diag[i] * TEMP_INV;
#pragma unroll
  for (int mm = 32; mm >= 1; mm >>= 1) rl += __shfl_xor(rl, mm, 64);
  __shared__ float red[4];
  if ((threadIdx.x & 63) == 0) red[threadIdx.x >> 6] = rl;
  __syncthreads();
  if (threadIdx.x == 0)
    atomicAdd(out, (red[0] + red[1] + red[2] + red[3]) / (float)Btot);
}

extern "C" void kernel_launch(void* const* d_in, const int* in_sizes, int n_in,
                              void* d_out, int out_size, void* d_ws, size_t ws_size,
                              hipStream_t stream) {
  const float* anchor   = (const float*)d_in[0];
  const float* positive = (const float*)d_in[1];
  const int B  = in_sizes[0] / DD;     // 8192
  const int NG = B / (BM * NCT);       // 8 column groups
  const size_t BD = (size_t)B * DD;

  // ws: a8(2MB) | p8(2MB, fragment-major) | rsum(NG*B) | rmax(NG*B) | diag(B)
  unsigned char* a8 = (unsigned char*)d_ws;
  unsigned char* p8 = a8 + BD;
  float* rsum  = (float*)(p8 + BD);
  float* rmax  = rsum + (size_t)NG * B;
  float* diag  = rmax + (size_t)NG * B;

  nrm_kernel<<<B / 16, 256, 0, stream>>>(anchor, positive, a8, p8, diag,
                                         (float*)d_out);
  dim3 g2(NG, B / BROWS);
  gemm_stats<<<g2, 512, 0, stream>>>(a8, p8, rsum, rmax, B);
  row_loss_kernel<<<B / 256, 256, 0, stream>>>(rsum, rmax, diag, (float*)d_out, B, NG);
}